// Round 12
// baseline (11600.894 us; speedup 1.0000x reference)
//
#include <hip/hip_runtime.h>

#define B_ 32
#define S_ 512
#define D_ 768
#define H_ 1024
#define L_ 4
#define TH 3072  // 3*H
#define NPL 32   // blocks per layer
#define NITER (S_ + L_ - 1)

typedef unsigned short u16;
typedef unsigned int u32;
typedef __bf16 bf16x8 __attribute__((ext_vector_type(8)));
typedef float f32x4 __attribute__((ext_vector_type(4)));
typedef unsigned int u32x2 __attribute__((ext_vector_type(2)));

__device__ __forceinline__ u16 f2b(float f) {
  unsigned u = __builtin_bit_cast(unsigned, f);
  u += 0x7fffu + ((u >> 16) & 1u);  // RNE
  return (u16)(u >> 16);
}
__device__ __forceinline__ float b2f(u16 h) {
  return __builtin_bit_cast(float, ((unsigned)h) << 16);
}
__device__ __forceinline__ unsigned pack2(float a, float b) {
  return (unsigned)f2b(a) | ((unsigned)f2b(b) << 16);
}

// ---------------- fp32 -> bf16 convert ----------------
__global__ __launch_bounds__(256) void cvt_kernel(const float* __restrict__ src,
                                                  u16* __restrict__ dst, int n4) {
  int i = blockIdx.x * 256 + threadIdx.x;
  int stride = gridDim.x * 256;
  for (; i < n4; i += stride) {
    float4 f = ((const float4*)src)[i];
    uint2 o;
    o.x = pack2(f.x, f.y);
    o.y = pack2(f.z, f.w);
    ((uint2*)dst)[i] = o;
  }
}

// ---------------- GI0 = (x+pos) @ W_ih0^T + b_ih[0]  -> bf16 [S*B][3072] ----------------
__global__ __launch_bounds__(256) void gi0_gemm(const float* __restrict__ x,
                                                const float* __restrict__ pos,
                                                const u16* __restrict__ W0,
                                                const float* __restrict__ bih0,
                                                u16* __restrict__ GI0) {
  const int n0 = blockIdx.x * 64;
  const int m0 = blockIdx.y * 64;
  __shared__ u16 sA[64 * 72];
  __shared__ u16 sB[64 * 72];
  const int tid = threadIdx.x, lane = tid & 63, wid = tid >> 6;
  const int wm = wid >> 1, wn = wid & 1;
  const int fr = lane & 15, fk = (lane >> 4) * 8;
  f32x4 acc[2][2] = {};
  for (int k0 = 0; k0 < D_; k0 += 64) {
    for (int sl = tid; sl < 512; sl += 256) {
      int r = sl >> 3, c = sl & 7;
      int m = m0 + r, si = m >> 5, b = m & 31;
      const float* xp = x + (size_t)((b << 9) + si) * D_ + k0 + c * 8;
      const float* pp = pos + (size_t)si * D_ + k0 + c * 8;
      float4 x0 = *(const float4*)xp, x1 = *(const float4*)(xp + 4);
      float4 p0 = *(const float4*)pp, p1 = *(const float4*)(pp + 4);
      uint4 o;
      o.x = pack2(x0.x + p0.x, x0.y + p0.y);
      o.y = pack2(x0.z + p0.z, x0.w + p0.w);
      o.z = pack2(x1.x + p1.x, x1.y + p1.y);
      o.w = pack2(x1.z + p1.z, x1.w + p1.w);
      *(uint4*)&sA[r * 72 + c * 8] = o;
      *(uint4*)&sB[r * 72 + c * 8] =
          *(const uint4*)(W0 + (size_t)(n0 + r) * D_ + k0 + c * 8);
    }
    __syncthreads();
#pragma unroll
    for (int kk = 0; kk < 2; ++kk) {
      bf16x8 a0 = *(const bf16x8*)&sA[(wm * 32 + fr) * 72 + kk * 32 + fk];
      bf16x8 a1 = *(const bf16x8*)&sA[(wm * 32 + 16 + fr) * 72 + kk * 32 + fk];
      bf16x8 b0 = *(const bf16x8*)&sB[(wn * 32 + fr) * 72 + kk * 32 + fk];
      bf16x8 b1 = *(const bf16x8*)&sB[(wn * 32 + 16 + fr) * 72 + kk * 32 + fk];
      acc[0][0] = __builtin_amdgcn_mfma_f32_16x16x32_bf16(a0, b0, acc[0][0], 0, 0, 0);
      acc[0][1] = __builtin_amdgcn_mfma_f32_16x16x32_bf16(a0, b1, acc[0][1], 0, 0, 0);
      acc[1][0] = __builtin_amdgcn_mfma_f32_16x16x32_bf16(a1, b0, acc[1][0], 0, 0, 0);
      acc[1][1] = __builtin_amdgcn_mfma_f32_16x16x32_bf16(a1, b1, acc[1][1], 0, 0, 0);
    }
    __syncthreads();
  }
#pragma unroll
  for (int mi = 0; mi < 2; ++mi)
#pragma unroll
    for (int ni = 0; ni < 2; ++ni)
#pragma unroll
      for (int r = 0; r < 4; ++r) {
        int m = m0 + wm * 32 + mi * 16 + (lane >> 4) * 4 + r;
        int n = n0 + wn * 32 + ni * 16 + fr;
        GI0[(size_t)m * TH + n] = f2b(acc[mi][ni][r] + bih0[n]);
      }
}

// ---------------- out_seq = H3 @ W_out^T + b_out ----------------
__global__ __launch_bounds__(256) void out_gemm(const u16* __restrict__ H3,
                                                const u16* __restrict__ Wo,
                                                const float* __restrict__ bo,
                                                float* __restrict__ out) {
  const int n0 = blockIdx.x * 64;
  const int m0 = blockIdx.y * 64;
  __shared__ u16 sA[64 * 72];
  __shared__ u16 sB[64 * 72];
  const int tid = threadIdx.x, lane = tid & 63, wid = tid >> 6;
  const int wm = wid >> 1, wn = wid & 1;
  const int fr = lane & 15, fk = (lane >> 4) * 8;
  f32x4 acc[2][2] = {};
  for (int k0 = 0; k0 < H_; k0 += 64) {
    for (int sl = tid; sl < 512; sl += 256) {
      int r = sl >> 3, c = sl & 7;
      int m = m0 + r, b = m >> 9, si = m & 511;
      *(uint4*)&sA[r * 72 + c * 8] =
          *(const uint4*)(H3 + (size_t)((si << 5) + b) * H_ + k0 + c * 8);
      *(uint4*)&sB[r * 72 + c * 8] =
          *(const uint4*)(Wo + (size_t)(n0 + r) * H_ + k0 + c * 8);
    }
    __syncthreads();
#pragma unroll
    for (int kk = 0; kk < 2; ++kk) {
      bf16x8 a0 = *(const bf16x8*)&sA[(wm * 32 + fr) * 72 + kk * 32 + fk];
      bf16x8 a1 = *(const bf16x8*)&sA[(wm * 32 + 16 + fr) * 72 + kk * 32 + fk];
      bf16x8 b0 = *(const bf16x8*)&sB[(wn * 32 + fr) * 72 + kk * 32 + fk];
      bf16x8 b1 = *(const bf16x8*)&sB[(wn * 32 + 16 + fr) * 72 + kk * 32 + fk];
      acc[0][0] = __builtin_amdgcn_mfma_f32_16x16x32_bf16(a0, b0, acc[0][0], 0, 0, 0);
      acc[0][1] = __builtin_amdgcn_mfma_f32_16x16x32_bf16(a0, b1, acc[0][1], 0, 0, 0);
      acc[1][0] = __builtin_amdgcn_mfma_f32_16x16x32_bf16(a1, b0, acc[1][0], 0, 0, 0);
      acc[1][1] = __builtin_amdgcn_mfma_f32_16x16x32_bf16(a1, b1, acc[1][1], 0, 0, 0);
    }
    __syncthreads();
  }
#pragma unroll
  for (int mi = 0; mi < 2; ++mi)
#pragma unroll
    for (int ni = 0; ni < 2; ++ni)
#pragma unroll
      for (int r = 0; r < 4; ++r) {
        int m = m0 + wm * 32 + mi * 16 + (lane >> 4) * 4 + r;
        int n = n0 + wn * 32 + ni * 16 + fr;
        out[(size_t)m * D_ + n] = acc[mi][ni][r] + bo[n];
      }
}

// ---------------- persistent weight-stationary GRU scan ----------------
// 128 blocks (32/layer), 256 threads (4 waves), __launch_bounds__(256,1).
// Each block owns 32 gate-triples (N=32). A-fragments (h) loaded directly
// from IF via sc0/sc1 (round-10 structure). Weight B-fragments streamed from
// L2 inside the MFMA loop via 6 row-base pointers (no big local array ->
// no scratch spill). h broadcast traffic: 16 MB/step (half of round 10).
// Flags: flags[L][32], plain sc0sc1 release after per-thread vmcnt(0);
// poll = wave 0, 3 fused loads + waitcnt in ONE asm (rule #18).
// h ring [L][4][32][1024]: writer (l,s)->buf s&3; WAR vs (l+1 @ s-3) guarded
// by flag[l+1] >= s-2; producers by flag[l-1] >= s, flag[l] >= s.
__global__ __launch_bounds__(256, 1) void rnn_persist(
    const u16* __restrict__ Whh, const u16* __restrict__ Wih,
    const u16* __restrict__ GI0, const float* __restrict__ bih,
    const float* __restrict__ bhh, u16* __restrict__ hg /* [L][4][32][1024] */,
    int* flags /* [L][32][16] */, u16* __restrict__ H3, float* __restrict__ hsf) {
  const int bid = blockIdx.x;
  const int l = bid >> 5;
  const int n0 = (bid & 31) << 5;
  const int tid = threadIdx.x, lane = tid & 63, wid = tid >> 6;
  const int fr = lane & 15, q = lane >> 4;
  const int l32 = lane & 31;

  __shared__ float red[4][3][32][33];

  // ---- weight row-base pointers (streamed from L2 in the MFMA loop) ----
  const u16* wrow[3][2];
  if (l == 0) {
    const int kb = wid << 8;  // K-quarter of Whh[0]
#pragma unroll
    for (int g = 0; g < 3; ++g)
#pragma unroll
      for (int nh = 0; nh < 2; ++nh)
        wrow[g][nh] =
            Whh + (((size_t)((g << 10) + n0 + nh * 16 + fr)) << 10) + kb;
  } else {
    const u16* Wp = (wid < 2) ? (Wih + (((size_t)(l - 1) * TH) << 10))
                              : (Whh + (((size_t)l * TH) << 10));
    const int kb = (wid & 1) << 9;  // K-half
#pragma unroll
    for (int g = 0; g < 3; ++g)
#pragma unroll
      for (int nh = 0; nh < 2; ++nh)
        wrow[g][nh] =
            Wp + (((size_t)((g << 10) + n0 + nh * 16 + fr)) << 10) + kb;
  }

  // poll pointers (wave 0; lanes 32-63 mirror lanes 0-31)
  const int* f_own = flags + ((l << 5) + l32) * 16;
  const int* f_m1 = (l > 0) ? flags + (((l - 1) << 5) + l32) * 16 : f_own;
  const int* f_p1 = (l < 3) ? flags + (((l + 1) << 5) + l32) * 16 : f_own;
  int* f_mine = flags + ((l << 5) + (bid & 31)) * 16;

  // gate-phase mapping: thread handles outputs (gb, gj..gj+3)
  const int gb = tid >> 3;         // 0..31 batch
  const int jj = (tid & 7) * 4;    // 0..28 within block's 32 triples
  const int gj = n0 + jj;
  float bihv[3][4], bhhv[3][4];
#pragma unroll
  for (int g = 0; g < 3; ++g)
#pragma unroll
    for (int u = 0; u < 4; ++u) {
      bihv[g][u] = (l > 0) ? bih[l * TH + (g << 10) + gj + u] : 0.f;
      bhhv[g][u] = bhh[l * TH + (g << 10) + gj + u];
    }
  float hpriv[4] = {0.f, 0.f, 0.f, 0.f};  // fp32 master copy
  __syncthreads();

  for (int s = 0; s < NITER; ++s) {
    const int t = s - l;
    if (t < 0 || t >= S_) {
      if (tid == 0) {
        int v = s + 1;
        asm volatile("global_store_dword %0, %1, off sc0 sc1" ::"v"(f_mine), "v"(v)
                     : "memory");
      }
      continue;
    }
    const int prev = (s - 1) & 3;

    // ---- prefetch GI0 (independent of handshake) ----
    u32x2 g0p = {0, 0}, g1p = {0, 0}, g2p = {0, 0};
    if (l == 0) {
      const u16* gp = GI0 + (size_t)((t << 5) + gb) * TH + gj;
      g0p = *(const u32x2*)gp;
      g1p = *(const u32x2*)(gp + 1024);
      g2p = *(const u32x2*)(gp + 2048);
    }

    // ---- wave-parallel distributed poll: loads+waitcnt FUSED in one asm ----
    if (wid == 0) {
      for (;;) {
        int fo, fm, fp;
        asm volatile(
            "global_load_dword %0, %3, off sc0 sc1\n\t"
            "global_load_dword %1, %4, off sc0 sc1\n\t"
            "global_load_dword %2, %5, off sc0 sc1\n\t"
            "s_waitcnt vmcnt(0)"
            : "=&v"(fo), "=&v"(fm), "=&v"(fp)
            : "v"(f_own), "v"(f_m1), "v"(f_p1)
            : "memory");
        __builtin_amdgcn_sched_barrier(0);
        bool ok = (fo >= s) && (fm >= s) && (fp >= s - 2);
        if (__all(ok)) break;
        __builtin_amdgcn_s_sleep(1);
      }
    }
    __syncthreads();

    // ---- MFMA phase: A (h) from IF sc0/sc1, B (weights) streamed from L2 ----
    f32x4 acc[2][2][3] = {};  // [m][nh][g]
    if (l == 0) {
      const u16* hp = hg + (prev << 15);
      const int kb = wid << 8;
      bf16x8 afr[2][8];
#pragma unroll
      for (int mt = 0; mt < 2; ++mt)
#pragma unroll
        for (int kt = 0; kt < 8; ++kt) {
          const u16* p = hp + (((mt << 4) + fr) << 10) + kb + kt * 32 + q * 8;
          asm volatile("global_load_dwordx4 %0, %1, off sc0 sc1"
                       : "=v"(afr[mt][kt]) : "v"(p) : "memory");
        }
      asm volatile("s_waitcnt vmcnt(0)" ::: "memory");
      __builtin_amdgcn_sched_barrier(0);
#pragma unroll
      for (int kt = 0; kt < 8; ++kt)
#pragma unroll
        for (int g = 0; g < 3; ++g)
#pragma unroll
          for (int nh = 0; nh < 2; ++nh) {
            bf16x8 b = *(const bf16x8*)(wrow[g][nh] + kt * 32 + q * 8);
            acc[0][nh][g] = __builtin_amdgcn_mfma_f32_16x16x32_bf16(afr[0][kt], b, acc[0][nh][g], 0, 0, 0);
            acc[1][nh][g] = __builtin_amdgcn_mfma_f32_16x16x32_bf16(afr[1][kt], b, acc[1][nh][g], 0, 0, 0);
          }
    } else {
      const u16* hsrc = (wid < 2) ? (hg + ((((l - 1) << 2) | prev) << 15))
                                  : (hg + (((l << 2) | prev) << 15));
      const int kb = (wid & 1) << 9;
      bf16x8 afr[2][16];
#pragma unroll
      for (int mt = 0; mt < 2; ++mt)
#pragma unroll
        for (int kt = 0; kt < 16; ++kt) {
          const u16* p = hsrc + (((mt << 4) + fr) << 10) + kb + kt * 32 + q * 8;
          asm volatile("global_load_dwordx4 %0, %1, off sc0 sc1"
                       : "=v"(afr[mt][kt]) : "v"(p) : "memory");
        }
      asm volatile("s_waitcnt vmcnt(0)" ::: "memory");
      __builtin_amdgcn_sched_barrier(0);
#pragma unroll
      for (int kt = 0; kt < 16; ++kt)
#pragma unroll
        for (int g = 0; g < 3; ++g)
#pragma unroll
          for (int nh = 0; nh < 2; ++nh) {
            bf16x8 b = *(const bf16x8*)(wrow[g][nh] + kt * 32 + q * 8);
            acc[0][nh][g] = __builtin_amdgcn_mfma_f32_16x16x32_bf16(afr[0][kt], b, acc[0][nh][g], 0, 0, 0);
            acc[1][nh][g] = __builtin_amdgcn_mfma_f32_16x16x32_bf16(afr[1][kt], b, acc[1][nh][g], 0, 0, 0);
          }
    }

    // ---- write partial sums to LDS ----
#pragma unroll
    for (int mt = 0; mt < 2; ++mt)
#pragma unroll
      for (int g = 0; g < 3; ++g)
#pragma unroll
        for (int nh = 0; nh < 2; ++nh)
#pragma unroll
          for (int r = 0; r < 4; ++r)
            red[wid][g][(mt << 4) + q * 4 + r][nh * 16 + fr] = acc[mt][nh][g][r];
    __syncthreads();

    // ---- gate math: 4 outputs per thread ----
    float gi[3][4], gh[3][4];
#pragma unroll
    for (int g = 0; g < 3; ++g)
#pragma unroll
      for (int u = 0; u < 4; ++u) {
        float s0 = red[0][g][gb][jj + u];
        float s1 = red[1][g][gb][jj + u];
        float s2 = red[2][g][gb][jj + u];
        float s3 = red[3][g][gb][jj + u];
        if (l == 0) {
          gh[g][u] = s0 + s1 + s2 + s3 + bhhv[g][u];
        } else {
          gi[g][u] = s0 + s1 + bihv[g][u];
          gh[g][u] = s2 + s3 + bhhv[g][u];
        }
      }
    if (l == 0) {
      gi[0][0] = b2f((u16)(g0p[0] & 0xffff));
      gi[0][1] = b2f((u16)(g0p[0] >> 16));
      gi[0][2] = b2f((u16)(g0p[1] & 0xffff));
      gi[0][3] = b2f((u16)(g0p[1] >> 16));
      gi[1][0] = b2f((u16)(g1p[0] & 0xffff));
      gi[1][1] = b2f((u16)(g1p[0] >> 16));
      gi[1][2] = b2f((u16)(g1p[1] & 0xffff));
      gi[1][3] = b2f((u16)(g1p[1] >> 16));
      gi[2][0] = b2f((u16)(g2p[0] & 0xffff));
      gi[2][1] = b2f((u16)(g2p[0] >> 16));
      gi[2][2] = b2f((u16)(g2p[1] & 0xffff));
      gi[2][3] = b2f((u16)(g2p[1] >> 16));
    }
    float hn[4];
#pragma unroll
    for (int u = 0; u < 4; ++u) {
      float rr = 1.f / (1.f + __expf(-(gi[0][u] + gh[0][u])));
      float zz = 1.f / (1.f + __expf(-(gi[1][u] + gh[1][u])));
      float xn = gi[2][u] + rr * gh[2][u];
      float nn = 1.f - 2.f / (__expf(2.f * xn) + 1.f);  // tanh, saturates correctly
      hn[u] = (1.f - zz) * nn + zz * hpriv[u];
      hpriv[u] = hn[u];
    }
    u32x2 hpack;
    hpack[0] = pack2(hn[0], hn[1]);
    hpack[1] = pack2(hn[2], hn[3]);
    u32* hd = (u32*)(hg + (((l << 2) | (s & 3)) << 15) + (gb << 10) + gj);
    asm volatile("global_store_dwordx2 %0, %1, off sc0 sc1" ::"v"(hd), "v"(hpack)
                 : "memory");
    asm volatile("s_waitcnt vmcnt(0)" ::: "memory");
    __syncthreads();
    // PLAIN-store publication on the block's private flag line.
    if (tid == 0) {
      int v = s + 1;
      asm volatile("global_store_dword %0, %1, off sc0 sc1" ::"v"(f_mine), "v"(v)
                   : "memory");
    }
    // non-protocol stores off the release path:
    if (l == 3) *(u32x2*)(H3 + (((size_t)(t << 5) + gb) << 10) + gj) = hpack;
    if (t == S_ - 1) {
      float4 hf = {hn[0], hn[1], hn[2], hn[3]};
      *(float4*)(hsf + ((l << 5) + gb) * 1024 + gj) = hf;
    }
  }
}

extern "C" void kernel_launch(void* const* d_in, const int* in_sizes, int n_in,
                              void* d_out, int out_size, void* d_ws, size_t ws_size,
                              hipStream_t stream) {
  const float* x = (const float*)d_in[0];
  const float* pos = (const float*)d_in[1];
  const float* Wih0 = (const float*)d_in[2];
  const float* Wih = (const float*)d_in[3];
  const float* Whh = (const float*)d_in[4];
  const float* bih = (const float*)d_in[5];
  const float* bhh = (const float*)d_in[6];
  const float* Wout = (const float*)d_in[7];
  const float* bout = (const float*)d_in[8];
  float* out = (float*)d_out;

  char* ws = (char*)d_ws;
  size_t o = 0;
  u16* wih0_b = (u16*)(ws + o); o += (size_t)TH * D_ * 2;
  u16* wih_b  = (u16*)(ws + o); o += (size_t)3 * TH * H_ * 2;
  u16* whh_b  = (u16*)(ws + o); o += (size_t)4 * TH * H_ * 2;
  u16* wout_b = (u16*)(ws + o); o += (size_t)D_ * H_ * 2;
  u16* GI0    = (u16*)(ws + o); o += (size_t)S_ * B_ * TH * 2;
  u16* H3     = (u16*)(ws + o); o += (size_t)S_ * B_ * H_ * 2;
  u16* hg     = (u16*)(ws + o); o += (size_t)L_ * 4 * B_ * H_ * 2;
  int* flags  = (int*)(ws + o); o += (size_t)L_ * 32 * 16 * 4;

  cvt_kernel<<<512, 256, 0, stream>>>(Wih0, wih0_b, TH * D_ / 4);
  cvt_kernel<<<512, 256, 0, stream>>>(Wih, wih_b, 3 * TH * H_ / 4);
  cvt_kernel<<<512, 256, 0, stream>>>(Whh, whh_b, 4 * TH * H_ / 4);
  cvt_kernel<<<512, 256, 0, stream>>>(Wout, wout_b, D_ * H_ / 4);
  hipMemsetAsync(hg, 0, (size_t)L_ * 4 * B_ * H_ * 2 + (size_t)L_ * 32 * 16 * 4,
                 stream);

  gi0_gemm<<<dim3(TH / 64, (S_ * B_) / 64), 256, 0, stream>>>(x, pos, wih0_b, bih, GI0);

  float* hsf = out + (size_t)B_ * S_ * D_;
  rnn_persist<<<128, 256, 0, stream>>>(whh_b, wih_b, GI0, bih, bhh, hg, flags, H3,
                                       hsf);

  out_gemm<<<dim3(D_ / 64, (S_ * B_) / 64), 256, 0, stream>>>(H3, wout_b, bout, out);
}

// Round 13
// 3529.473 us; speedup vs baseline: 3.2869x; 3.2869x over previous
//
#include <hip/hip_runtime.h>

#define B_ 32
#define S_ 512
#define D_ 768
#define H_ 1024
#define L_ 4
#define TH 3072  // 3*H
#define NPL 64   // blocks per layer
#define NITER (S_ + L_ - 1)

typedef unsigned short u16;
typedef unsigned int u32;
typedef __bf16 bf16x8 __attribute__((ext_vector_type(8)));
typedef float f32x4 __attribute__((ext_vector_type(4)));

__device__ __forceinline__ u16 f2b(float f) {
  unsigned u = __builtin_bit_cast(unsigned, f);
  u += 0x7fffu + ((u >> 16) & 1u);  // RNE
  return (u16)(u >> 16);
}
__device__ __forceinline__ float b2f(u16 h) {
  return __builtin_bit_cast(float, ((unsigned)h) << 16);
}
__device__ __forceinline__ unsigned pack2(float a, float b) {
  return (unsigned)f2b(a) | ((unsigned)f2b(b) << 16);
}

// ---------------- fp32 -> bf16 convert ----------------
__global__ __launch_bounds__(256) void cvt_kernel(const float* __restrict__ src,
                                                  u16* __restrict__ dst, int n4) {
  int i = blockIdx.x * 256 + threadIdx.x;
  int stride = gridDim.x * 256;
  for (; i < n4; i += stride) {
    float4 f = ((const float4*)src)[i];
    uint2 o;
    o.x = pack2(f.x, f.y);
    o.y = pack2(f.z, f.w);
    ((uint2*)dst)[i] = o;
  }
}

// ---------------- GI0 = (x+pos) @ W_ih0^T + b_ih[0]  -> bf16 [S*B][3072] ----------------
__global__ __launch_bounds__(256) void gi0_gemm(const float* __restrict__ x,
                                                const float* __restrict__ pos,
                                                const u16* __restrict__ W0,
                                                const float* __restrict__ bih0,
                                                u16* __restrict__ GI0) {
  const int n0 = blockIdx.x * 64;
  const int m0 = blockIdx.y * 64;
  __shared__ u16 sA[64 * 72];
  __shared__ u16 sB[64 * 72];
  const int tid = threadIdx.x, lane = tid & 63, wid = tid >> 6;
  const int wm = wid >> 1, wn = wid & 1;
  const int fr = lane & 15, fk = (lane >> 4) * 8;
  f32x4 acc[2][2] = {};
  for (int k0 = 0; k0 < D_; k0 += 64) {
    for (int sl = tid; sl < 512; sl += 256) {
      int r = sl >> 3, c = sl & 7;
      int m = m0 + r, si = m >> 5, b = m & 31;
      const float* xp = x + (size_t)((b << 9) + si) * D_ + k0 + c * 8;
      const float* pp = pos + (size_t)si * D_ + k0 + c * 8;
      float4 x0 = *(const float4*)xp, x1 = *(const float4*)(xp + 4);
      float4 p0 = *(const float4*)pp, p1 = *(const float4*)(pp + 4);
      uint4 o;
      o.x = pack2(x0.x + p0.x, x0.y + p0.y);
      o.y = pack2(x0.z + p0.z, x0.w + p0.w);
      o.z = pack2(x1.x + p1.x, x1.y + p1.y);
      o.w = pack2(x1.z + p1.z, x1.w + p1.w);
      *(uint4*)&sA[r * 72 + c * 8] = o;
      *(uint4*)&sB[r * 72 + c * 8] =
          *(const uint4*)(W0 + (size_t)(n0 + r) * D_ + k0 + c * 8);
    }
    __syncthreads();
#pragma unroll
    for (int kk = 0; kk < 2; ++kk) {
      bf16x8 a0 = *(const bf16x8*)&sA[(wm * 32 + fr) * 72 + kk * 32 + fk];
      bf16x8 a1 = *(const bf16x8*)&sA[(wm * 32 + 16 + fr) * 72 + kk * 32 + fk];
      bf16x8 b0 = *(const bf16x8*)&sB[(wn * 32 + fr) * 72 + kk * 32 + fk];
      bf16x8 b1 = *(const bf16x8*)&sB[(wn * 32 + 16 + fr) * 72 + kk * 32 + fk];
      acc[0][0] = __builtin_amdgcn_mfma_f32_16x16x32_bf16(a0, b0, acc[0][0], 0, 0, 0);
      acc[0][1] = __builtin_amdgcn_mfma_f32_16x16x32_bf16(a0, b1, acc[0][1], 0, 0, 0);
      acc[1][0] = __builtin_amdgcn_mfma_f32_16x16x32_bf16(a1, b0, acc[1][0], 0, 0, 0);
      acc[1][1] = __builtin_amdgcn_mfma_f32_16x16x32_bf16(a1, b1, acc[1][1], 0, 0, 0);
    }
    __syncthreads();
  }
#pragma unroll
  for (int mi = 0; mi < 2; ++mi)
#pragma unroll
    for (int ni = 0; ni < 2; ++ni)
#pragma unroll
      for (int r = 0; r < 4; ++r) {
        int m = m0 + wm * 32 + mi * 16 + (lane >> 4) * 4 + r;
        int n = n0 + wn * 32 + ni * 16 + fr;
        GI0[(size_t)m * TH + n] = f2b(acc[mi][ni][r] + bih0[n]);
      }
}

// ---------------- out_seq = H3 @ W_out^T + b_out ----------------
__global__ __launch_bounds__(256) void out_gemm(const u16* __restrict__ H3,
                                                const u16* __restrict__ Wo,
                                                const float* __restrict__ bo,
                                                float* __restrict__ out) {
  const int n0 = blockIdx.x * 64;
  const int m0 = blockIdx.y * 64;
  __shared__ u16 sA[64 * 72];
  __shared__ u16 sB[64 * 72];
  const int tid = threadIdx.x, lane = tid & 63, wid = tid >> 6;
  const int wm = wid >> 1, wn = wid & 1;
  const int fr = lane & 15, fk = (lane >> 4) * 8;
  f32x4 acc[2][2] = {};
  for (int k0 = 0; k0 < H_; k0 += 64) {
    for (int sl = tid; sl < 512; sl += 256) {
      int r = sl >> 3, c = sl & 7;
      int m = m0 + r, b = m >> 9, si = m & 511;
      *(uint4*)&sA[r * 72 + c * 8] =
          *(const uint4*)(H3 + (size_t)((si << 5) + b) * H_ + k0 + c * 8);
      *(uint4*)&sB[r * 72 + c * 8] =
          *(const uint4*)(Wo + (size_t)(n0 + r) * H_ + k0 + c * 8);
    }
    __syncthreads();
#pragma unroll
    for (int kk = 0; kk < 2; ++kk) {
      bf16x8 a0 = *(const bf16x8*)&sA[(wm * 32 + fr) * 72 + kk * 32 + fk];
      bf16x8 a1 = *(const bf16x8*)&sA[(wm * 32 + 16 + fr) * 72 + kk * 32 + fk];
      bf16x8 b0 = *(const bf16x8*)&sB[(wn * 32 + fr) * 72 + kk * 32 + fk];
      bf16x8 b1 = *(const bf16x8*)&sB[(wn * 32 + 16 + fr) * 72 + kk * 32 + fk];
      acc[0][0] = __builtin_amdgcn_mfma_f32_16x16x32_bf16(a0, b0, acc[0][0], 0, 0, 0);
      acc[0][1] = __builtin_amdgcn_mfma_f32_16x16x32_bf16(a0, b1, acc[0][1], 0, 0, 0);
      acc[1][0] = __builtin_amdgcn_mfma_f32_16x16x32_bf16(a1, b0, acc[1][0], 0, 0, 0);
      acc[1][1] = __builtin_amdgcn_mfma_f32_16x16x32_bf16(a1, b1, acc[1][1], 0, 0, 0);
    }
    __syncthreads();
  }
#pragma unroll
  for (int mi = 0; mi < 2; ++mi)
#pragma unroll
    for (int ni = 0; ni < 2; ++ni)
#pragma unroll
      for (int r = 0; r < 4; ++r) {
        int m = m0 + wm * 32 + mi * 16 + (lane >> 4) * 4 + r;
        int n = n0 + wn * 32 + ni * 16 + fr;
        out[(size_t)m * D_ + n] = acc[mi][ni][r] + bo[n];
      }
}

// ---------------- persistent weight-stationary GRU scan ----------------
// 256 blocks (64/layer), 512 threads (8 waves), __launch_bounds__(512,1).
// Block owns 16 gate-triples. Waves l>0: (mat=wid>>2, kq=wid&3) — weights
// w[3][8] = 96 VGPRs/lane, truly register-resident (no scratch, no per-step
// weight traffic). l==0: wave = K-eighth of Whh, w[3][4]=48 VGPRs.
// Sync: per-wave decoupled ENTRY poll (ih waves: f_m1>=s; hh waves: f_own>=s;
// no pre-MFMA barrier — each wave's loads guarded by its own poll). WAR poll
// (f_p1 >= s-2) by wave 7 after reduce-write, overlapped with reduce, fenced
// by the post-reduce barrier. 2 barriers/step. Release: h stores sc0sc1 ->
// per-thread vmcnt(0) -> barrier -> tid0 plain sc0sc1 flag store.
// h ring [L][4][32][1024]: writer (l,s)->buf s&3; WAR vs (l+1 @ s-3).
__global__ __launch_bounds__(512, 1) void rnn_persist(
    const u16* __restrict__ Whh, const u16* __restrict__ Wih,
    const u16* __restrict__ GI0, const float* __restrict__ bih,
    const float* __restrict__ bhh, u16* __restrict__ hg /* [L][4][32][1024] */,
    int* flags /* [L][64][16] */, u16* __restrict__ H3, float* __restrict__ hsf) {
  const int bid = blockIdx.x;
  const int l = bid >> 6;
  const int n0 = (bid & 63) << 4;
  const int tid = threadIdx.x, lane = tid & 63, wid = tid >> 6;
  const int fr = lane & 15, q = lane >> 4;

  __shared__ float red[8][3][32][17];

  // ---- preload weights into registers (true residency) ----
  bf16x8 w[3][8];
  if (l == 0) {
    const int kb = wid << 7;  // K-eighth of Whh[0]
#pragma unroll
    for (int g = 0; g < 3; ++g)
#pragma unroll
      for (int kt = 0; kt < 4; ++kt)
        w[g][kt] = *(const bf16x8*)(Whh + (((size_t)((g << 10) + n0 + fr)) << 10) +
                                    kb + kt * 32 + q * 8);
  } else {
    const int mat = wid >> 2;
    const u16* Wp = (mat == 0) ? (Wih + (((size_t)(l - 1) * TH) << 10))
                               : (Whh + (((size_t)l * TH) << 10));
    const int kb = (wid & 3) << 8;  // K-quarter
#pragma unroll
    for (int g = 0; g < 3; ++g)
#pragma unroll
      for (int kt = 0; kt < 8; ++kt)
        w[g][kt] = *(const bf16x8*)(Wp + (((size_t)((g << 10) + n0 + fr)) << 10) +
                                    kb + kt * 32 + q * 8);
  }

  // flag pointers: lane i watches flag line i (64 lines/layer)
  const int* f_own = flags + ((l << 6) + lane) * 16;
  const int* f_m1 = (l > 0) ? flags + (((l - 1) << 6) + lane) * 16 : f_own;
  const int* f_p1 = (l < 3) ? flags + (((l + 1) << 6) + lane) * 16 : f_own;
  int* f_mine = flags + ((l << 6) + (bid & 63)) * 16;
  // entry-poll pointer for this wave
  const int* pw = (l > 0 && wid < 4) ? f_m1 : f_own;

  // gate-phase mapping: thread handles one output (gb, gj)
  const int gb = tid >> 4;        // 0..31 batch
  const int jj = tid & 15;        // 0..15 within block's triples
  const int gj = n0 + jj;
  float bihv[3], bhhv[3];
#pragma unroll
  for (int g = 0; g < 3; ++g) {
    bihv[g] = (l > 0) ? bih[l * TH + (g << 10) + gj] : 0.f;
    bhhv[g] = bhh[l * TH + (g << 10) + gj];
  }
  float hpriv = 0.f;  // fp32 master copy of this thread's h value
  __syncthreads();

  for (int s = 0; s < NITER; ++s) {
    const int t = s - l;
    if (t < 0 || t >= S_) {
      if (tid == 0) {
        int v = s + 1;
        asm volatile("global_store_dword %0, %1, off sc0 sc1" ::"v"(f_mine), "v"(v)
                     : "memory");
      }
      continue;
    }
    const int prev = (s - 1) & 3;

    // ---- prefetch GI0 (independent of handshake) ----
    float gp0 = 0.f, gp1 = 0.f, gp2 = 0.f;
    if (l == 0) {
      const u16* gp = GI0 + (size_t)((t << 5) + gb) * TH + gj;
      gp0 = b2f(gp[0]);
      gp1 = b2f(gp[1024]);
      gp2 = b2f(gp[2048]);
    }

    // ---- per-wave decoupled entry poll (fused load+waitcnt, rule #18) ----
    for (;;) {
      int fv;
      asm volatile("global_load_dword %0, %1, off sc0 sc1\n\ts_waitcnt vmcnt(0)"
                   : "=v"(fv) : "v"(pw) : "memory");
      __builtin_amdgcn_sched_barrier(0);
      if (__all(fv >= s)) break;
      __builtin_amdgcn_s_sleep(1);
    }

    // ---- MFMA phase: A (h) from IF sc0/sc1, weights from VGPRs ----
    f32x4 acc[2][3] = {};
    if (l == 0) {
      const u16* hp = hg + (prev << 15);
      const int kb = wid << 7;
      bf16x8 afr[2][4];
#pragma unroll
      for (int mt = 0; mt < 2; ++mt)
#pragma unroll
        for (int kt = 0; kt < 4; ++kt) {
          const u16* p = hp + (((mt << 4) + fr) << 10) + kb + kt * 32 + q * 8;
          asm volatile("global_load_dwordx4 %0, %1, off sc0 sc1"
                       : "=v"(afr[mt][kt]) : "v"(p) : "memory");
        }
      asm volatile("s_waitcnt vmcnt(0)" ::: "memory");
      __builtin_amdgcn_sched_barrier(0);
#pragma unroll
      for (int kt = 0; kt < 4; ++kt)
#pragma unroll
        for (int g = 0; g < 3; ++g) {
          acc[0][g] = __builtin_amdgcn_mfma_f32_16x16x32_bf16(afr[0][kt], w[g][kt], acc[0][g], 0, 0, 0);
          acc[1][g] = __builtin_amdgcn_mfma_f32_16x16x32_bf16(afr[1][kt], w[g][kt], acc[1][g], 0, 0, 0);
        }
    } else {
      const u16* hsrc = (wid < 4) ? (hg + ((((l - 1) << 2) | prev) << 15))
                                  : (hg + (((l << 2) | prev) << 15));
      const int kb = (wid & 3) << 8;
      bf16x8 afr[2][8];
#pragma unroll
      for (int mt = 0; mt < 2; ++mt)
#pragma unroll
        for (int kt = 0; kt < 8; ++kt) {
          const u16* p = hsrc + (((mt << 4) + fr) << 10) + kb + kt * 32 + q * 8;
          asm volatile("global_load_dwordx4 %0, %1, off sc0 sc1"
                       : "=v"(afr[mt][kt]) : "v"(p) : "memory");
        }
      asm volatile("s_waitcnt vmcnt(0)" ::: "memory");
      __builtin_amdgcn_sched_barrier(0);
#pragma unroll
      for (int kt = 0; kt < 8; ++kt)
#pragma unroll
        for (int g = 0; g < 3; ++g) {
          acc[0][g] = __builtin_amdgcn_mfma_f32_16x16x32_bf16(afr[0][kt], w[g][kt], acc[0][g], 0, 0, 0);
          acc[1][g] = __builtin_amdgcn_mfma_f32_16x16x32_bf16(afr[1][kt], w[g][kt], acc[1][g], 0, 0, 0);
        }
    }

    // ---- write partial sums to LDS ----
#pragma unroll
    for (int mt = 0; mt < 2; ++mt)
#pragma unroll
      for (int g = 0; g < 3; ++g)
#pragma unroll
        for (int r = 0; r < 4; ++r)
          red[wid][g][(mt << 4) + q * 4 + r][fr] = acc[mt][g][r];

    // ---- WAR poll overlapped with other waves' reduce (wave 7 only) ----
    if (wid == 7) {
      const int thr = s - 2;
      for (;;) {
        int fv;
        asm volatile("global_load_dword %0, %1, off sc0 sc1\n\ts_waitcnt vmcnt(0)"
                     : "=v"(fv) : "v"(f_p1) : "memory");
        __builtin_amdgcn_sched_barrier(0);
        if (__all(fv >= thr)) break;
        __builtin_amdgcn_s_sleep(1);
      }
    }
    __syncthreads();

    // ---- gate math: 1 output per thread ----
    float gi[3], gh[3];
#pragma unroll
    for (int g = 0; g < 3; ++g) {
      float s0 = red[0][g][gb][jj] + red[1][g][gb][jj];
      float s1 = red[2][g][gb][jj] + red[3][g][gb][jj];
      float s2 = red[4][g][gb][jj] + red[5][g][gb][jj];
      float s3 = red[6][g][gb][jj] + red[7][g][gb][jj];
      if (l == 0) {
        gh[g] = s0 + s1 + s2 + s3 + bhhv[g];
      } else {
        gi[g] = s0 + s1 + bihv[g];
        gh[g] = s2 + s3 + bhhv[g];
      }
    }
    if (l == 0) {
      gi[0] = gp0;
      gi[1] = gp1;
      gi[2] = gp2;
    }
    float rr = 1.f / (1.f + __expf(-(gi[0] + gh[0])));
    float zz = 1.f / (1.f + __expf(-(gi[1] + gh[1])));
    float xn = gi[2] + rr * gh[2];
    float nn = 1.f - 2.f / (__expf(2.f * xn) + 1.f);  // tanh, saturates correctly
    float hn = (1.f - zz) * nn + zz * hpriv;
    hpriv = hn;
    u16 hb = f2b(hn);
    u16* hd = hg + (((l << 2) | (s & 3)) << 15) + (gb << 10) + gj;
    {
      u32 hv = hb;
      asm volatile("global_store_short %0, %1, off sc0 sc1" ::"v"(hd), "v"(hv)
                   : "memory");
    }
    asm volatile("s_waitcnt vmcnt(0)" ::: "memory");
    __syncthreads();
    // PLAIN-store publication on the block's private flag line.
    if (tid == 0) {
      int v = s + 1;
      asm volatile("global_store_dword %0, %1, off sc0 sc1" ::"v"(f_mine), "v"(v)
                   : "memory");
    }
    // non-protocol stores off the release path:
    if (l == 3) H3[(((size_t)(t << 5) + gb) << 10) + gj] = hb;
    if (t == S_ - 1) hsf[((l << 5) + gb) * 1024 + gj] = hn;
  }
}

extern "C" void kernel_launch(void* const* d_in, const int* in_sizes, int n_in,
                              void* d_out, int out_size, void* d_ws, size_t ws_size,
                              hipStream_t stream) {
  const float* x = (const float*)d_in[0];
  const float* pos = (const float*)d_in[1];
  const float* Wih0 = (const float*)d_in[2];
  const float* Wih = (const float*)d_in[3];
  const float* Whh = (const float*)d_in[4];
  const float* bih = (const float*)d_in[5];
  const float* bhh = (const float*)d_in[6];
  const float* Wout = (const float*)d_in[7];
  const float* bout = (const float*)d_in[8];
  float* out = (float*)d_out;

  char* ws = (char*)d_ws;
  size_t o = 0;
  u16* wih0_b = (u16*)(ws + o); o += (size_t)TH * D_ * 2;
  u16* wih_b  = (u16*)(ws + o); o += (size_t)3 * TH * H_ * 2;
  u16* whh_b  = (u16*)(ws + o); o += (size_t)4 * TH * H_ * 2;
  u16* wout_b = (u16*)(ws + o); o += (size_t)D_ * H_ * 2;
  u16* GI0    = (u16*)(ws + o); o += (size_t)S_ * B_ * TH * 2;
  u16* H3     = (u16*)(ws + o); o += (size_t)S_ * B_ * H_ * 2;
  u16* hg     = (u16*)(ws + o); o += (size_t)L_ * 4 * B_ * H_ * 2;
  int* flags  = (int*)(ws + o); o += (size_t)L_ * 64 * 16 * 4;

  cvt_kernel<<<512, 256, 0, stream>>>(Wih0, wih0_b, TH * D_ / 4);
  cvt_kernel<<<512, 256, 0, stream>>>(Wih, wih_b, 3 * TH * H_ / 4);
  cvt_kernel<<<512, 256, 0, stream>>>(Whh, whh_b, 4 * TH * H_ / 4);
  cvt_kernel<<<512, 256, 0, stream>>>(Wout, wout_b, D_ * H_ / 4);
  hipMemsetAsync(hg, 0, (size_t)L_ * 4 * B_ * H_ * 2 + (size_t)L_ * 64 * 16 * 4,
                 stream);

  gi0_gemm<<<dim3(TH / 64, (S_ * B_) / 64), 256, 0, stream>>>(x, pos, wih0_b, bih, GI0);

  float* hsf = out + (size_t)B_ * S_ * D_;
  rnn_persist<<<256, 512, 0, stream>>>(whh_b, wih_b, GI0, bih, bhh, hg, flags, H3,
                                       hsf);

  out_gemm<<<dim3(D_ / 64, (S_ * B_) / 64), 256, 0, stream>>>(H3, wout_b, bout, out);
}

// Round 14
// 3390.981 us; speedup vs baseline: 3.4211x; 1.0408x over previous
//
#include <hip/hip_runtime.h>

#define B_ 32
#define S_ 512
#define D_ 768
#define H_ 1024
#define L_ 4
#define TH 3072  // 3*H
#define NPL 64   // blocks per layer
#define NITER (S_ + L_ - 1)

typedef unsigned short u16;
typedef unsigned int u32;
typedef __bf16 bf16x8 __attribute__((ext_vector_type(8)));
typedef float f32x4 __attribute__((ext_vector_type(4)));

__device__ __forceinline__ u16 f2b(float f) {
  unsigned u = __builtin_bit_cast(unsigned, f);
  u += 0x7fffu + ((u >> 16) & 1u);  // RNE
  return (u16)(u >> 16);
}
__device__ __forceinline__ float b2f(u16 h) {
  return __builtin_bit_cast(float, ((unsigned)h) << 16);
}
__device__ __forceinline__ unsigned pack2(float a, float b) {
  return (unsigned)f2b(a) | ((unsigned)f2b(b) << 16);
}

// ---------------- fp32 -> bf16 convert ----------------
__global__ __launch_bounds__(256) void cvt_kernel(const float* __restrict__ src,
                                                  u16* __restrict__ dst, int n4) {
  int i = blockIdx.x * 256 + threadIdx.x;
  int stride = gridDim.x * 256;
  for (; i < n4; i += stride) {
    float4 f = ((const float4*)src)[i];
    uint2 o;
    o.x = pack2(f.x, f.y);
    o.y = pack2(f.z, f.w);
    ((uint2*)dst)[i] = o;
  }
}

// ---------------- GI0 = (x+pos) @ W_ih0^T + b_ih[0]  -> bf16 [S*B][3072] ----------------
__global__ __launch_bounds__(256) void gi0_gemm(const float* __restrict__ x,
                                                const float* __restrict__ pos,
                                                const u16* __restrict__ W0,
                                                const float* __restrict__ bih0,
                                                u16* __restrict__ GI0) {
  const int n0 = blockIdx.x * 64;
  const int m0 = blockIdx.y * 64;
  __shared__ u16 sA[64 * 72];
  __shared__ u16 sB[64 * 72];
  const int tid = threadIdx.x, lane = tid & 63, wid = tid >> 6;
  const int wm = wid >> 1, wn = wid & 1;
  const int fr = lane & 15, fk = (lane >> 4) * 8;
  f32x4 acc[2][2] = {};
  for (int k0 = 0; k0 < D_; k0 += 64) {
    for (int sl = tid; sl < 512; sl += 256) {
      int r = sl >> 3, c = sl & 7;
      int m = m0 + r, si = m >> 5, b = m & 31;
      const float* xp = x + (size_t)((b << 9) + si) * D_ + k0 + c * 8;
      const float* pp = pos + (size_t)si * D_ + k0 + c * 8;
      float4 x0 = *(const float4*)xp, x1 = *(const float4*)(xp + 4);
      float4 p0 = *(const float4*)pp, p1 = *(const float4*)(pp + 4);
      uint4 o;
      o.x = pack2(x0.x + p0.x, x0.y + p0.y);
      o.y = pack2(x0.z + p0.z, x0.w + p0.w);
      o.z = pack2(x1.x + p1.x, x1.y + p1.y);
      o.w = pack2(x1.z + p1.z, x1.w + p1.w);
      *(uint4*)&sA[r * 72 + c * 8] = o;
      *(uint4*)&sB[r * 72 + c * 8] =
          *(const uint4*)(W0 + (size_t)(n0 + r) * D_ + k0 + c * 8);
    }
    __syncthreads();
#pragma unroll
    for (int kk = 0; kk < 2; ++kk) {
      bf16x8 a0 = *(const bf16x8*)&sA[(wm * 32 + fr) * 72 + kk * 32 + fk];
      bf16x8 a1 = *(const bf16x8*)&sA[(wm * 32 + 16 + fr) * 72 + kk * 32 + fk];
      bf16x8 b0 = *(const bf16x8*)&sB[(wn * 32 + fr) * 72 + kk * 32 + fk];
      bf16x8 b1 = *(const bf16x8*)&sB[(wn * 32 + 16 + fr) * 72 + kk * 32 + fk];
      acc[0][0] = __builtin_amdgcn_mfma_f32_16x16x32_bf16(a0, b0, acc[0][0], 0, 0, 0);
      acc[0][1] = __builtin_amdgcn_mfma_f32_16x16x32_bf16(a0, b1, acc[0][1], 0, 0, 0);
      acc[1][0] = __builtin_amdgcn_mfma_f32_16x16x32_bf16(a1, b0, acc[1][0], 0, 0, 0);
      acc[1][1] = __builtin_amdgcn_mfma_f32_16x16x32_bf16(a1, b1, acc[1][1], 0, 0, 0);
    }
    __syncthreads();
  }
#pragma unroll
  for (int mi = 0; mi < 2; ++mi)
#pragma unroll
    for (int ni = 0; ni < 2; ++ni)
#pragma unroll
      for (int r = 0; r < 4; ++r) {
        int m = m0 + wm * 32 + mi * 16 + (lane >> 4) * 4 + r;
        int n = n0 + wn * 32 + ni * 16 + fr;
        GI0[(size_t)m * TH + n] = f2b(acc[mi][ni][r] + bih0[n]);
      }
}

// ---------------- out_seq = H3 @ W_out^T + b_out ----------------
__global__ __launch_bounds__(256) void out_gemm(const u16* __restrict__ H3,
                                                const u16* __restrict__ Wo,
                                                const float* __restrict__ bo,
                                                float* __restrict__ out) {
  const int n0 = blockIdx.x * 64;
  const int m0 = blockIdx.y * 64;
  __shared__ u16 sA[64 * 72];
  __shared__ u16 sB[64 * 72];
  const int tid = threadIdx.x, lane = tid & 63, wid = tid >> 6;
  const int wm = wid >> 1, wn = wid & 1;
  const int fr = lane & 15, fk = (lane >> 4) * 8;
  f32x4 acc[2][2] = {};
  for (int k0 = 0; k0 < H_; k0 += 64) {
    for (int sl = tid; sl < 512; sl += 256) {
      int r = sl >> 3, c = sl & 7;
      int m = m0 + r, b = m >> 9, si = m & 511;
      *(uint4*)&sA[r * 72 + c * 8] =
          *(const uint4*)(H3 + (size_t)((si << 5) + b) * H_ + k0 + c * 8);
      *(uint4*)&sB[r * 72 + c * 8] =
          *(const uint4*)(Wo + (size_t)(n0 + r) * H_ + k0 + c * 8);
    }
    __syncthreads();
#pragma unroll
    for (int kk = 0; kk < 2; ++kk) {
      bf16x8 a0 = *(const bf16x8*)&sA[(wm * 32 + fr) * 72 + kk * 32 + fk];
      bf16x8 a1 = *(const bf16x8*)&sA[(wm * 32 + 16 + fr) * 72 + kk * 32 + fk];
      bf16x8 b0 = *(const bf16x8*)&sB[(wn * 32 + fr) * 72 + kk * 32 + fk];
      bf16x8 b1 = *(const bf16x8*)&sB[(wn * 32 + 16 + fr) * 72 + kk * 32 + fk];
      acc[0][0] = __builtin_amdgcn_mfma_f32_16x16x32_bf16(a0, b0, acc[0][0], 0, 0, 0);
      acc[0][1] = __builtin_amdgcn_mfma_f32_16x16x32_bf16(a0, b1, acc[0][1], 0, 0, 0);
      acc[1][0] = __builtin_amdgcn_mfma_f32_16x16x32_bf16(a1, b0, acc[1][0], 0, 0, 0);
      acc[1][1] = __builtin_amdgcn_mfma_f32_16x16x32_bf16(a1, b1, acc[1][1], 0, 0, 0);
    }
    __syncthreads();
  }
#pragma unroll
  for (int mi = 0; mi < 2; ++mi)
#pragma unroll
    for (int ni = 0; ni < 2; ++ni)
#pragma unroll
      for (int r = 0; r < 4; ++r) {
        int m = m0 + wm * 32 + mi * 16 + (lane >> 4) * 4 + r;
        int n = n0 + wn * 32 + ni * 16 + fr;
        out[(size_t)m * D_ + n] = acc[mi][ni][r] + bo[n];
      }
}

// ---------------- persistent weight-stationary GRU scan ----------------
// 256 blocks (64/layer), 512 threads (8 waves), __launch_bounds__(512,1).
// Block owns 16 gate-triples. Waves l>0: (mat=wid>>2, kq=wid&3).
// ENTRY poll is per-wave and K-RANGE-FINE: a wave reading columns
// kb..kb+255 of layer X polls only the 16 flags of the layer-X blocks that
// own those columns (8 flags for l==0's 128-wide K-eighth) — rendezvous
// width 16 instead of 64, so each wave's IF loads start as early as
// possible. WAR poll (f_p1 >= s-2, all 64 consumer flags) by wave 7 after
// its reduce-write, fenced by the post-reduce barrier (unchanged safety
// argument). red buffer stride 17 -> 20: write banks (16q+20r+fr)%32 and
// read banks (20gb+jj)%32 are both <=2-way (free, m136).
// Release: h stores sc0sc1 -> per-thread vmcnt(0) -> barrier -> tid0 plain
// sc0sc1 flag store. h ring [L][4][32][1024]: writer (l,s)->buf s&3.
__global__ __launch_bounds__(512, 1) void rnn_persist(
    const u16* __restrict__ Whh, const u16* __restrict__ Wih,
    const u16* __restrict__ GI0, const float* __restrict__ bih,
    const float* __restrict__ bhh, u16* __restrict__ hg /* [L][4][32][1024] */,
    int* flags /* [L][64][16] */, u16* __restrict__ H3, float* __restrict__ hsf) {
  const int bid = blockIdx.x;
  const int l = bid >> 6;
  const int n0 = (bid & 63) << 4;
  const int tid = threadIdx.x, lane = tid & 63, wid = tid >> 6;
  const int fr = lane & 15, q = lane >> 4;

  __shared__ float red[8][3][32][20];

  // ---- preload weights into registers (compiler may stream from L2) ----
  bf16x8 w[3][8];
  if (l == 0) {
    const int kb = wid << 7;  // K-eighth of Whh[0]
#pragma unroll
    for (int g = 0; g < 3; ++g)
#pragma unroll
      for (int kt = 0; kt < 4; ++kt)
        w[g][kt] = *(const bf16x8*)(Whh + (((size_t)((g << 10) + n0 + fr)) << 10) +
                                    kb + kt * 32 + q * 8);
  } else {
    const int mat = wid >> 2;
    const u16* Wp = (mat == 0) ? (Wih + (((size_t)(l - 1) * TH) << 10))
                               : (Whh + (((size_t)l * TH) << 10));
    const int kb = (wid & 3) << 8;  // K-quarter
#pragma unroll
    for (int g = 0; g < 3; ++g)
#pragma unroll
      for (int kt = 0; kt < 8; ++kt)
        w[g][kt] = *(const bf16x8*)(Wp + (((size_t)((g << 10) + n0 + fr)) << 10) +
                                    kb + kt * 32 + q * 8);
  }

  // ---- per-wave fine-grained entry-poll pointer (K-range producers) ----
  // producer block p of layer X owns columns p*16..p*16+15.
  const int* pw;
  if (l == 0) {
    // wave reads cols wid*128..+127 of layer 0 -> 8 producer blocks
    pw = flags + ((0 << 6) + (wid << 3) + (lane & 7)) * 16;
  } else {
    const int srcl = (wid < 4) ? (l - 1) : l;
    pw = flags + ((srcl << 6) + ((wid & 3) << 4) + (lane & 15)) * 16;
  }
  // WAR pointer: lane i watches consumer-layer flag line i (64 lines)
  const int* f_p1 = (l < 3) ? flags + (((l + 1) << 6) + lane) * 16
                            : flags + ((l << 6) + lane) * 16;
  int* f_mine = flags + ((l << 6) + (bid & 63)) * 16;

  // gate-phase mapping: thread handles one output (gb, gj)
  const int gb = tid >> 4;        // 0..31 batch
  const int jj = tid & 15;        // 0..15 within block's triples
  const int gj = n0 + jj;
  float bihv[3], bhhv[3];
#pragma unroll
  for (int g = 0; g < 3; ++g) {
    bihv[g] = (l > 0) ? bih[l * TH + (g << 10) + gj] : 0.f;
    bhhv[g] = bhh[l * TH + (g << 10) + gj];
  }
  float hpriv = 0.f;  // fp32 master copy of this thread's h value
  __syncthreads();

  for (int s = 0; s < NITER; ++s) {
    const int t = s - l;
    if (t < 0 || t >= S_) {
      if (tid == 0) {
        int v = s + 1;
        asm volatile("global_store_dword %0, %1, off sc0 sc1" ::"v"(f_mine), "v"(v)
                     : "memory");
      }
      continue;
    }
    const int prev = (s - 1) & 3;

    // ---- prefetch GI0 (independent of handshake) ----
    float gp0 = 0.f, gp1 = 0.f, gp2 = 0.f;
    if (l == 0) {
      const u16* gp = GI0 + (size_t)((t << 5) + gb) * TH + gj;
      gp0 = b2f(gp[0]);
      gp1 = b2f(gp[1024]);
      gp2 = b2f(gp[2048]);
    }

    // ---- per-wave K-range entry poll (fused load+waitcnt, rule #18) ----
    for (;;) {
      int fv;
      asm volatile("global_load_dword %0, %1, off sc0 sc1\n\ts_waitcnt vmcnt(0)"
                   : "=v"(fv) : "v"(pw) : "memory");
      __builtin_amdgcn_sched_barrier(0);
      if (__all(fv >= s)) break;
      __builtin_amdgcn_s_sleep(1);
    }

    // ---- MFMA phase: A (h) from IF sc0/sc1, weights from VGPRs/L2 ----
    f32x4 acc[2][3] = {};
    if (l == 0) {
      const u16* hp = hg + (prev << 15);
      const int kb = wid << 7;
      bf16x8 afr[2][4];
#pragma unroll
      for (int mt = 0; mt < 2; ++mt)
#pragma unroll
        for (int kt = 0; kt < 4; ++kt) {
          const u16* p = hp + (((mt << 4) + fr) << 10) + kb + kt * 32 + q * 8;
          asm volatile("global_load_dwordx4 %0, %1, off sc0 sc1"
                       : "=v"(afr[mt][kt]) : "v"(p) : "memory");
        }
      asm volatile("s_waitcnt vmcnt(0)" ::: "memory");
      __builtin_amdgcn_sched_barrier(0);
#pragma unroll
      for (int kt = 0; kt < 4; ++kt)
#pragma unroll
        for (int g = 0; g < 3; ++g) {
          acc[0][g] = __builtin_amdgcn_mfma_f32_16x16x32_bf16(afr[0][kt], w[g][kt], acc[0][g], 0, 0, 0);
          acc[1][g] = __builtin_amdgcn_mfma_f32_16x16x32_bf16(afr[1][kt], w[g][kt], acc[1][g], 0, 0, 0);
        }
    } else {
      const u16* hsrc = (wid < 4) ? (hg + ((((l - 1) << 2) | prev) << 15))
                                  : (hg + (((l << 2) | prev) << 15));
      const int kb = (wid & 3) << 8;
      bf16x8 afr[2][8];
#pragma unroll
      for (int mt = 0; mt < 2; ++mt)
#pragma unroll
        for (int kt = 0; kt < 8; ++kt) {
          const u16* p = hsrc + (((mt << 4) + fr) << 10) + kb + kt * 32 + q * 8;
          asm volatile("global_load_dwordx4 %0, %1, off sc0 sc1"
                       : "=v"(afr[mt][kt]) : "v"(p) : "memory");
        }
      asm volatile("s_waitcnt vmcnt(0)" ::: "memory");
      __builtin_amdgcn_sched_barrier(0);
#pragma unroll
      for (int kt = 0; kt < 8; ++kt)
#pragma unroll
        for (int g = 0; g < 3; ++g) {
          acc[0][g] = __builtin_amdgcn_mfma_f32_16x16x32_bf16(afr[0][kt], w[g][kt], acc[0][g], 0, 0, 0);
          acc[1][g] = __builtin_amdgcn_mfma_f32_16x16x32_bf16(afr[1][kt], w[g][kt], acc[1][g], 0, 0, 0);
        }
    }

    // ---- write partial sums to LDS ----
#pragma unroll
    for (int mt = 0; mt < 2; ++mt)
#pragma unroll
      for (int g = 0; g < 3; ++g)
#pragma unroll
        for (int r = 0; r < 4; ++r)
          red[wid][g][(mt << 4) + q * 4 + r][fr] = acc[mt][g][r];

    // ---- WAR poll overlapped with other waves' reduce (wave 7 only) ----
    if (wid == 7) {
      const int thr = s - 2;
      for (;;) {
        int fv;
        asm volatile("global_load_dword %0, %1, off sc0 sc1\n\ts_waitcnt vmcnt(0)"
                     : "=v"(fv) : "v"(f_p1) : "memory");
        __builtin_amdgcn_sched_barrier(0);
        if (__all(fv >= thr)) break;
        __builtin_amdgcn_s_sleep(1);
      }
    }
    __syncthreads();

    // ---- gate math: 1 output per thread ----
    float gi[3], gh[3];
#pragma unroll
    for (int g = 0; g < 3; ++g) {
      float s0 = red[0][g][gb][jj] + red[1][g][gb][jj];
      float s1 = red[2][g][gb][jj] + red[3][g][gb][jj];
      float s2 = red[4][g][gb][jj] + red[5][g][gb][jj];
      float s3 = red[6][g][gb][jj] + red[7][g][gb][jj];
      if (l == 0) {
        gh[g] = s0 + s1 + s2 + s3 + bhhv[g];
      } else {
        gi[g] = s0 + s1 + bihv[g];
        gh[g] = s2 + s3 + bhhv[g];
      }
    }
    if (l == 0) {
      gi[0] = gp0;
      gi[1] = gp1;
      gi[2] = gp2;
    }
    float rr = 1.f / (1.f + __expf(-(gi[0] + gh[0])));
    float zz = 1.f / (1.f + __expf(-(gi[1] + gh[1])));
    float xn = gi[2] + rr * gh[2];
    float nn = 1.f - 2.f / (__expf(2.f * xn) + 1.f);  // tanh, saturates correctly
    float hn = (1.f - zz) * nn + zz * hpriv;
    hpriv = hn;
    u16 hb = f2b(hn);
    u16* hd = hg + (((l << 2) | (s & 3)) << 15) + (gb << 10) + gj;
    {
      u32 hv = hb;
      asm volatile("global_store_short %0, %1, off sc0 sc1" ::"v"(hd), "v"(hv)
                   : "memory");
    }
    asm volatile("s_waitcnt vmcnt(0)" ::: "memory");
    __syncthreads();
    // PLAIN-store publication on the block's private flag line.
    if (tid == 0) {
      int v = s + 1;
      asm volatile("global_store_dword %0, %1, off sc0 sc1" ::"v"(f_mine), "v"(v)
                   : "memory");
    }
    // non-protocol stores off the release path:
    if (l == 3) H3[(((size_t)(t << 5) + gb) << 10) + gj] = hb;
    if (t == S_ - 1) hsf[((l << 5) + gb) * 1024 + gj] = hn;
  }
}

extern "C" void kernel_launch(void* const* d_in, const int* in_sizes, int n_in,
                              void* d_out, int out_size, void* d_ws, size_t ws_size,
                              hipStream_t stream) {
  const float* x = (const float*)d_in[0];
  const float* pos = (const float*)d_in[1];
  const float* Wih0 = (const float*)d_in[2];
  const float* Wih = (const float*)d_in[3];
  const float* Whh = (const float*)d_in[4];
  const float* bih = (const float*)d_in[5];
  const float* bhh = (const float*)d_in[6];
  const float* Wout = (const float*)d_in[7];
  const float* bout = (const float*)d_in[8];
  float* out = (float*)d_out;

  char* ws = (char*)d_ws;
  size_t o = 0;
  u16* wih0_b = (u16*)(ws + o); o += (size_t)TH * D_ * 2;
  u16* wih_b  = (u16*)(ws + o); o += (size_t)3 * TH * H_ * 2;
  u16* whh_b  = (u16*)(ws + o); o += (size_t)4 * TH * H_ * 2;
  u16* wout_b = (u16*)(ws + o); o += (size_t)D_ * H_ * 2;
  u16* GI0    = (u16*)(ws + o); o += (size_t)S_ * B_ * TH * 2;
  u16* H3     = (u16*)(ws + o); o += (size_t)S_ * B_ * H_ * 2;
  u16* hg     = (u16*)(ws + o); o += (size_t)L_ * 4 * B_ * H_ * 2;
  int* flags  = (int*)(ws + o); o += (size_t)L_ * 64 * 16 * 4;

  cvt_kernel<<<512, 256, 0, stream>>>(Wih0, wih0_b, TH * D_ / 4);
  cvt_kernel<<<512, 256, 0, stream>>>(Wih, wih_b, 3 * TH * H_ / 4);
  cvt_kernel<<<512, 256, 0, stream>>>(Whh, whh_b, 4 * TH * H_ / 4);
  cvt_kernel<<<512, 256, 0, stream>>>(Wout, wout_b, D_ * H_ / 4);
  hipMemsetAsync(hg, 0, (size_t)L_ * 4 * B_ * H_ * 2 + (size_t)L_ * 64 * 16 * 4,
                 stream);

  gi0_gemm<<<dim3(TH / 64, (S_ * B_) / 64), 256, 0, stream>>>(x, pos, wih0_b, bih, GI0);

  float* hsf = out + (size_t)B_ * S_ * D_;
  rnn_persist<<<256, 512, 0, stream>>>(whh_b, wih_b, GI0, bih, bhh, hg, flags, H3,
                                       hsf);

  out_gemm<<<dim3(D_ / 64, (S_ * B_) / 64), 256, 0, stream>>>(H3, wout_b, bout, out);
}